// Round 7
// baseline (510.633 us; speedup 1.0000x reference)
//
#include <hip/hip_runtime.h>
#include <math.h>

#define NN 100000
#define EE 1600000
#define GG 512
#define INF_ 128
#define HID 64
#define EPS 1e-5f

#define NBUK 391          // ceil(NN/256), bucket = dst >> 8
#define P1_TILES 98       // ceil((EE/4)/4096)
#define NGRP 25000        // ceil(NN/4) node groups for gather

typedef unsigned int uint32;
typedef __attribute__((ext_vector_type(8))) short bf16x8;
typedef __attribute__((ext_vector_type(4))) float f32x4;

// bf16 helpers: RNE pack, shift decode
static __device__ inline uint32 f2bf(float f) {
    uint32 u = __float_as_uint(f);
    return (u + 0x7FFFu + ((u >> 16) & 1u)) >> 16;
}
static __device__ inline float bf_lo(uint32 u) { return __uint_as_float(u << 16); }
static __device__ inline float bf_hi(uint32 u) { return __uint_as_float(u & 0xFFFF0000u); }

// Chunked layouts (4 chunks of 16 features):
//   hwb_c : uint32 [4][NN][8]   (bf16 pairs)  — 3.2 MB/chunk, fits 4MiB XCD L2
//   h_c   : float  [4][NN][16]

// ---------------- CSR build: 2-level counting sort ----------------
// R3: per-edge atomic scatter had 12x write amplification from cross-XCD
// line bouncing. Block-aggregated bucket sort keeps lines block-owned.

__global__ __launch_bounds__(256) void k_bhist(const int* __restrict__ ei,
                                               int* __restrict__ bcnt) {
    __shared__ int h[NBUK];
    int t = threadIdx.x;
    for (int i = t; i < NBUK; i += 256) h[i] = 0;
    __syncthreads();
    const int4* dst4 = (const int4*)(ei + EE);
    int base4 = blockIdx.x * 4096;
    for (int j = 0; j < 16; ++j) {
        int i4 = base4 + j * 256 + t;
        if (i4 < EE / 4) {
            int4 d = dst4[i4];
            atomicAdd(&h[d.x >> 8], 1);
            atomicAdd(&h[d.y >> 8], 1);
            atomicAdd(&h[d.z >> 8], 1);
            atomicAdd(&h[d.w >> 8], 1);
        }
    }
    __syncthreads();
    for (int i = t; i < NBUK; i += 256)
        if (h[i]) atomicAdd(&bcnt[i], h[i]);
}

__global__ void k_bscan(const int* __restrict__ bcnt, int* __restrict__ bbase,
                        int* __restrict__ gcur, int* __restrict__ offs) {
    __shared__ int wsum[8];
    int t = threadIdx.x;  // 512
    int lane = t & 63, w = t >> 6;
    int c = (t < NBUK) ? bcnt[t] : 0;
    int v = c;
    for (int d = 1; d < 64; d <<= 1) { int n = __shfl_up(v, d); if (lane >= d) v += n; }
    if (lane == 63) wsum[w] = v;
    __syncthreads();
    int pre = 0;
    for (int q = 0; q < w; ++q) pre += wsum[q];
    int excl = pre + v - c;
    if (t <= NBUK) {
        bbase[t] = excl;
        if (t < NBUK) gcur[t] = excl;
    }
    if (t == 0) offs[NN] = EE;
}

// scatter packed (src<<8)|(dst&255) into CSR-ordered bucket regions
__global__ __launch_bounds__(256) void k_p1(const int* __restrict__ ei,
                                            int* __restrict__ gcur,
                                            uint32* __restrict__ pairs) {
    __shared__ int h[NBUK];
    int t = threadIdx.x;
    for (int i = t; i < NBUK; i += 256) h[i] = 0;
    __syncthreads();
    const int4* src4 = (const int4*)ei;
    const int4* dst4 = (const int4*)(ei + EE);
    int base4 = blockIdx.x * 4096;
    for (int j = 0; j < 16; ++j) {
        int i4 = base4 + j * 256 + t;
        if (i4 < EE / 4) {
            int4 d = dst4[i4];
            atomicAdd(&h[d.x >> 8], 1);
            atomicAdd(&h[d.y >> 8], 1);
            atomicAdd(&h[d.z >> 8], 1);
            atomicAdd(&h[d.w >> 8], 1);
        }
    }
    __syncthreads();
    for (int i = t; i < NBUK; i += 256) {
        int c = h[i];
        h[i] = c ? atomicAdd(&gcur[i], c) : 0;
    }
    __syncthreads();
    for (int j = 0; j < 16; ++j) {
        int i4 = base4 + j * 256 + t;
        if (i4 < EE / 4) {
            int4 d = dst4[i4];
            int4 s = src4[i4];
            int p0 = atomicAdd(&h[d.x >> 8], 1);
            pairs[p0] = ((uint32)s.x << 8) | (uint32)(d.x & 255);
            int p1 = atomicAdd(&h[d.y >> 8], 1);
            pairs[p1] = ((uint32)s.y << 8) | (uint32)(d.y & 255);
            int p2 = atomicAdd(&h[d.z >> 8], 1);
            pairs[p2] = ((uint32)s.z << 8) | (uint32)(d.z & 255);
            int p3 = atomicAdd(&h[d.w >> 8], 1);
            pairs[p3] = ((uint32)s.w << 8) | (uint32)(d.w & 255);
        }
    }
}

// per-bucket (256 nodes) CSR finalize in LDS: count, scan, scatter col
__global__ __launch_bounds__(256) void k_p2(const uint32* __restrict__ pairs,
                                            const int* __restrict__ bbase,
                                            int* __restrict__ offs, float* __restrict__ dinv,
                                            int* __restrict__ col) {
    int b = blockIdx.x, t = threadIdx.x;
    int nbase = b << 8;
    int ebase = bbase[b], eend = bbase[b + 1];
    int m = eend - ebase;
    __shared__ int cnt[256];
    __shared__ int wsum[4];
    cnt[t] = 0;
    __syncthreads();
    for (int i = t; i < m; i += 256)
        atomicAdd(&cnt[pairs[ebase + i] & 255u], 1);
    __syncthreads();
    int c = cnt[t];
    int lane = t & 63, w = t >> 6;
    int v = c;
    for (int d = 1; d < 64; d <<= 1) { int n = __shfl_up(v, d); if (lane >= d) v += n; }
    if (lane == 63) wsum[w] = v;
    __syncthreads();
    int pre = 0;
    for (int q = 0; q < w; ++q) pre += wsum[q];
    int excl = pre + v - c;
    int node = nbase + t;
    if (node < NN) {
        offs[node] = ebase + excl;
        dinv[node] = rsqrtf(1.f + (float)c);
    }
    __syncthreads();
    cnt[t] = excl;
    __syncthreads();
    for (int i = t; i < m; i += 256) {
        uint32 u = pairs[ebase + i];
        int loc = atomicAdd(&cnt[u & 255u], 1);
        col[ebase + loc] = (int)(u >> 8);
    }
}

// ---------------- BN constant folding ----------------
__global__ void k_precompute_bn(const float* b1, const float* g1, const float* be1,
                                const float* rm1, const float* rv1,
                                const float* b2, const float* g2, const float* be2,
                                const float* rm2, const float* rv2, float* sc) {
    int l = threadIdx.x;
    float s1 = g1[l] * rsqrtf(rv1[l] + EPS);
    sc[l]       = s1;
    sc[64 + l]  = (b1[l] - rm1[l]) * s1 + be1[l];
    float s2 = g2[l] * rsqrtf(rv2[l] + EPS);
    sc[128 + l] = s2;
    sc[192 + l] = (b2[l] - rm2[l]) * s2 + be2[l];
}

// ---------------- weight transpose+bf16: W[K][64] -> Wtb[64][K/2 uints] ----
__global__ void k_wt(const float* __restrict__ W, uint32* __restrict__ Wtb, int K) {
    int i = blockIdx.x * 256 + threadIdx.x;
    if (i >= 64 * K / 2) return;
    int n = i / (K / 2), kp = (i % (K / 2)) * 2;
    Wtb[i] = f2bf(W[(size_t)kp * 64 + n]) | (f2bf(W[(size_t)(kp + 1) * 64 + n]) << 16);
}

// ---------------- MFMA GEMM -> chunk-major bf16 packed output -------------
// 64x64 tile/block, 4 waves x 4 n-tiles x K/32 k-steps, 16x16x32 bf16 MFMA.
// XSRC=0: X = f32 row-major [nrows][K]. XSRC=1: X = chunked f32 h_c [4][NN][16].
template <int K, int XSRC>
__global__ __launch_bounds__(256) void k_gemm_mfma(const float* __restrict__ X,
                                                   const uint32* __restrict__ Wtb,
                                                   uint32* __restrict__ outb, int nrows) {
    constexpr int KP = K + 8;
    __shared__ alignas(16) unsigned short Al[64 * KP];
    __shared__ alignas(16) unsigned short Bl[64 * KP];
    int tid = threadIdx.x;
    for (int i = tid; i < 64 * (K / 2); i += 256) {
        int n = i / (K / 2), kp = i % (K / 2);
        *(uint32*)&Bl[n * KP + kp * 2] = Wtb[i];
    }
    int r0 = blockIdx.x * 64;
    for (int f = tid * 4; f < 64 * K; f += 1024) {
        int row = f / K, kpos = f % K;
        int grow = r0 + row;
        float4 v = {0.f, 0.f, 0.f, 0.f};
        if (grow < nrows) {
            if (XSRC == 0)
                v = *(const float4*)&X[(size_t)grow * K + kpos];
            else
                v = *(const float4*)&X[(size_t)(kpos >> 4) * NN * 16 +
                                       (size_t)grow * 16 + (kpos & 15)];
        }
        ushort4 pk;
        pk.x = (unsigned short)f2bf(v.x);
        pk.y = (unsigned short)f2bf(v.y);
        pk.z = (unsigned short)f2bf(v.z);
        pk.w = (unsigned short)f2bf(v.w);
        *(ushort4*)&Al[row * KP + kpos] = pk;
    }
    __syncthreads();
    int lane = tid & 63, wv = tid >> 6;
    int m = lane & 15, quad = lane >> 4;
    f32x4 acc0 = {0.f, 0.f, 0.f, 0.f}, acc1 = acc0, acc2 = acc0, acc3 = acc0;
    int arow = wv * 16 + m;
#pragma unroll
    for (int k0 = 0; k0 < K; k0 += 32) {
        int koff = k0 + quad * 8;
        bf16x8 a = *(const bf16x8*)&Al[arow * KP + koff];
        bf16x8 b0 = *(const bf16x8*)&Bl[(0 * 16 + m) * KP + koff];
        bf16x8 b1 = *(const bf16x8*)&Bl[(1 * 16 + m) * KP + koff];
        bf16x8 b2 = *(const bf16x8*)&Bl[(2 * 16 + m) * KP + koff];
        bf16x8 b3 = *(const bf16x8*)&Bl[(3 * 16 + m) * KP + koff];
        acc0 = __builtin_amdgcn_mfma_f32_16x16x32_bf16(a, b0, acc0, 0, 0, 0);
        acc1 = __builtin_amdgcn_mfma_f32_16x16x32_bf16(a, b1, acc1, 0, 0, 0);
        acc2 = __builtin_amdgcn_mfma_f32_16x16x32_bf16(a, b2, acc2, 0, 0, 0);
        acc3 = __builtin_amdgcn_mfma_f32_16x16x32_bf16(a, b3, acc3, 0, 0, 0);
    }
    // C/D: col = nt*16 + m, row = quad*4 + reg. chunk = nt (16 features).
    const float* accs[4] = {(const float*)&acc0, (const float*)&acc1,
                            (const float*)&acc2, (const float*)&acc3};
#pragma unroll
    for (int nt = 0; nt < 4; ++nt) {
#pragma unroll
        for (int reg = 0; reg < 4; ++reg) {
            float val = accs[nt][reg];
            float nxt = __shfl_down(val, 1);
            int row = r0 + wv * 16 + quad * 4 + reg;
            if (((m & 1) == 0) && row < nrows)
                outb[(size_t)nt * NN * 8 + (size_t)row * 8 + (m >> 1)] =
                    f2bf(val) | (f2bf(nxt) << 16);
        }
    }
}

// ---- fused GCN aggregate + selfloop + BN + ReLU (+resid), XCD-chunked ----
// chunk = blockIdx&3: with round-robin block->XCD dispatch (%8), XCD k only
// touches chunk k%4 (3.2 MB, L2-resident). 8 lanes/edge -> 8 edges/step.
__global__ __launch_bounds__(256) void k_gcn_gather(
        const uint32* __restrict__ hwb, const int* __restrict__ col,
        const int* __restrict__ offs, const float* __restrict__ dinv,
        const float* __restrict__ scale, const float* __restrict__ shift,
        const float* __restrict__ resid, float* __restrict__ out) {
    int chunk = blockIdx.x & 3;
    int node = (blockIdx.x >> 2) * 4 + (threadIdx.x >> 6);
    if (node >= NN) return;
    int lane = threadIdx.x & 63;
    int upos = lane & 7;                 // uint in chunk row (features 2u,2u+1)
    int eslot = lane >> 3;               // 8 parallel edges
    const uint32* hc = hwb + (size_t)chunk * NN * 8;
    int e0 = offs[node], e1 = offs[node + 1];
    float di = dinv[node];
    float ax = 0.f, ay = 0.f;
    for (int base = e0; base < e1; base += 64) {
        int m = e1 - base; if (m > 64) m = 64;
        int srcv = 0; float wv = 0.f;
        if (lane < m) { srcv = col[base + lane]; wv = dinv[srcv]; }
        for (int j = 0; j < m; j += 8) {
            int   s = __shfl(srcv, j + eslot);   // 0 for slots >= m -> w=0
            float w = __shfl(wv,   j + eslot);
            uint32 u = hc[(size_t)s * 8 + upos];
            ax = fmaf(bf_lo(u), w, ax);
            ay = fmaf(bf_hi(u), w, ay);
        }
    }
    // reduce over the 8 edge slots (stride 8,16,32 butterfly)
    ax += __shfl_xor(ax, 8);  ay += __shfl_xor(ay, 8);
    ax += __shfl_xor(ax, 16); ay += __shfl_xor(ay, 16);
    ax += __shfl_xor(ax, 32); ay += __shfl_xor(ay, 32);
    if (eslot == 0) {
        int fg = chunk * 16 + 2 * upos;          // global feature index
        uint32 uself = hc[(size_t)node * 8 + upos];
        float dii = di * di;
        float vx = fmaf(ax * di + bf_lo(uself) * dii, scale[fg],     shift[fg]);
        float vy = fmaf(ay * di + bf_hi(uself) * dii, scale[fg + 1], shift[fg + 1]);
        vx = fmaxf(vx, 0.f);
        vy = fmaxf(vy, 0.f);
        size_t oidx = (size_t)chunk * NN * 16 + (size_t)node * 16 + 2 * upos;
        if (resid) {
            float2 rv = *(const float2*)&resid[oidx];
            vx += rv.x; vy += rv.y;
        }
        float2 o; o.x = vx; o.y = vy;
        *(float2*)&out[oidx] = o;
    }
}

// ---------------- pooling over sorted batch (chunked h_c input) -----------
__global__ void k_pool(const float* __restrict__ h, const int* __restrict__ batch,
                       float* __restrict__ msum, float* __restrict__ mmax,
                       float* __restrict__ gcnt) {
    int lane = threadIdx.x;  // 64; feature = lane; chunk = lane>>4
    size_t rbase = (size_t)(lane >> 4) * NN * 16 + (lane & 15);
    int i0 = blockIdx.x * 128;
    int i1 = i0 + 128; if (i1 > NN) i1 = NN;
    int cur = batch[i0];
    float sum = 0.f, mx = 0.f; int c = 0;
    for (int i = i0; i < i1; ++i) {
        int g = batch[i];
        if (g != cur) {
            atomicAdd(&msum[cur * 64 + lane], sum);
            atomicMax((unsigned int*)&mmax[cur * 64 + lane], __float_as_uint(mx));
            if (lane == 0) atomicAdd(&gcnt[cur], (float)c);
            sum = 0.f; mx = 0.f; c = 0; cur = g;
        }
        float v = h[rbase + (size_t)i * 16];
        sum += v; mx = fmaxf(mx, v); ++c;
    }
    atomicAdd(&msum[cur * 64 + lane], sum);
    atomicMax((unsigned int*)&mmax[cur * 64 + lane], __float_as_uint(mx));
    if (lane == 0) atomicAdd(&gcnt[cur], (float)c);
}

// ---------------- MLP head, one block per graph ----------------
__global__ void k_head(const float* __restrict__ msum, const float* __restrict__ mmax,
                       const float* __restrict__ gcnt,
                       const float* __restrict__ Wh1, const float* __restrict__ bh1,
                       const float* __restrict__ Wh2, const float* __restrict__ bh2,
                       const float* __restrict__ Wh3, const float* __restrict__ bh3,
                       float* __restrict__ out) {
    int g = blockIdx.x, t = threadIdx.x;  // 64 threads
    __shared__ float hg[128];
    __shared__ float z1[64];
    __shared__ float z2[32];
    float c = fmaxf(gcnt[g], 1.f);
    hg[t]      = msum[g * 64 + t] / c;
    hg[64 + t] = mmax[g * 64 + t];
    __syncthreads();
    float acc = bh1[t];
#pragma unroll 8
    for (int k = 0; k < 128; ++k) acc = fmaf(hg[k], Wh1[k * 64 + t], acc);
    z1[t] = fmaxf(acc, 0.f);
    __syncthreads();
    if (t < 32) {
        float a2 = bh2[t];
#pragma unroll 8
        for (int k = 0; k < 64; ++k) a2 = fmaf(z1[k], Wh2[k * 32 + t], a2);
        z2[t] = fmaxf(a2, 0.f);
    }
    __syncthreads();
    if (t == 0) {
        float a3 = bh3[0];
        for (int k = 0; k < 32; ++k) a3 = fmaf(z2[k], Wh3[k], a3);
        out[g] = 1.f / (1.f + expf(-a3));
    }
}

// ---------------- launcher ----------------

static inline size_t alignup(size_t x) { return (x + 255) & ~(size_t)255; }

extern "C" void kernel_launch(void* const* d_in, const int* in_sizes, int n_in,
                              void* d_out, int out_size, void* d_ws, size_t ws_size,
                              hipStream_t stream) {
    const float* x   = (const float*)d_in[0];
    const int*   ei  = (const int*)d_in[1];
    const int*   bat = (const int*)d_in[2];
    const float* W1  = (const float*)d_in[3];
    const float* b1  = (const float*)d_in[4];
    const float* g1  = (const float*)d_in[5];
    const float* be1 = (const float*)d_in[6];
    const float* rm1 = (const float*)d_in[7];
    const float* rv1 = (const float*)d_in[8];
    const float* W2  = (const float*)d_in[9];
    const float* b2  = (const float*)d_in[10];
    const float* g2  = (const float*)d_in[11];
    const float* be2 = (const float*)d_in[12];
    const float* rm2 = (const float*)d_in[13];
    const float* rv2 = (const float*)d_in[14];
    const float* Wh1 = (const float*)d_in[15];
    const float* bh1 = (const float*)d_in[16];
    const float* Wh2 = (const float*)d_in[17];
    const float* bh2 = (const float*)d_in[18];
    const float* Wh3 = (const float*)d_in[19];
    const float* bh3 = (const float*)d_in[20];
    float* out = (float*)d_out;

    char* ws = (char*)d_ws;
    size_t o = 0;
    int*   bcnt   = (int*)(ws + o);  o = alignup(o + NBUK * 4);
    int*   bbase  = (int*)(ws + o);  o = alignup(o + (NBUK + 1) * 4);
    int*   gcur   = (int*)(ws + o);  o = alignup(o + NBUK * 4);
    int*   offs   = (int*)(ws + o);  o = alignup(o + (NN + 1) * 4);
    uint32* pairs = (uint32*)(ws + o); o = alignup(o + (size_t)EE * 4);
    int*   col    = (int*)(ws + o);  o = alignup(o + (size_t)EE * 4);
    float* dinv   = (float*)(ws + o); o = alignup(o + (size_t)NN * 4);
    float* scb    = (float*)(ws + o); o = alignup(o + 4 * 64 * 4);
    uint32* Wt1b  = (uint32*)(ws + o); o = alignup(o + 64 * (INF_ / 2) * 4);
    uint32* Wt2b  = (uint32*)(ws + o); o = alignup(o + 64 * (HID / 2) * 4);
    float* msum   = (float*)(ws + o);
    size_t pool_off = o;              o += (size_t)GG * 64 * 4;
    float* mmax   = (float*)(ws + o); o += (size_t)GG * 64 * 4;
    float* gcnt   = (float*)(ws + o); o += (size_t)GG * 4;
    size_t pool_bytes = o - pool_off; o = alignup(o);
    uint32* hwb   = (uint32*)(ws + o); o = alignup(o + (size_t)NN * 32 * 4);
    float* h      = (float*)(ws + o); o = alignup(o + (size_t)NN * 64 * 4);
    (void)ws_size; (void)n_in; (void)in_sizes; (void)out_size;

    hipMemsetAsync(bcnt, 0, NBUK * 4, stream);
    hipMemsetAsync(ws + pool_off, 0, pool_bytes, stream);

    k_precompute_bn<<<1, 64, 0, stream>>>(b1, g1, be1, rm1, rv1, b2, g2, be2, rm2, rv2, scb);
    k_wt<<<(64 * (INF_ / 2) + 255) / 256, 256, 0, stream>>>(W1, Wt1b, INF_);
    k_wt<<<(64 * (HID / 2) + 255) / 256, 256, 0, stream>>>(W2, Wt2b, HID);
    k_bhist<<<P1_TILES, 256, 0, stream>>>(ei, bcnt);
    k_bscan<<<1, 512, 0, stream>>>(bcnt, bbase, gcur, offs);
    k_p1<<<P1_TILES, 256, 0, stream>>>(ei, gcur, pairs);
    k_p2<<<NBUK, 256, 0, stream>>>(pairs, bbase, offs, dinv, col);

    // layer 1
    k_gemm_mfma<INF_, 0><<<(NN + 63) / 64, 256, 0, stream>>>(x, Wt1b, hwb, NN);
    k_gcn_gather<<<NGRP * 4, 256, 0, stream>>>(hwb, col, offs, dinv,
                                               scb, scb + 64, nullptr, h);
    // layer 2 (residual, in-place into chunked h)
    k_gemm_mfma<HID, 1><<<(NN + 63) / 64, 256, 0, stream>>>(h, Wt2b, hwb, NN);
    k_gcn_gather<<<NGRP * 4, 256, 0, stream>>>(hwb, col, offs, dinv,
                                               scb + 128, scb + 192, h, h);
    // pooling + head
    k_pool<<<(NN + 127) / 128, 64, 0, stream>>>(h, bat, msum, mmax, gcnt);
    k_head<<<GG, 64, 0, stream>>>(msum, mmax, gcnt, Wh1, bh1, Wh2, bh2, Wh3, bh3, out);
}

// Round 8
// 335.037 us; speedup vs baseline: 1.5241x; 1.5241x over previous
//
#include <hip/hip_runtime.h>
#include <math.h>

#define NN 100000
#define EE 1600000
#define GG 512
#define INF_ 128
#define HID 64
#define EPS 1e-5f

#define NBUK 391          // ceil(NN/256), bucket = dst >> 8
#define P1_TILES 98       // ceil((EE/4)/4096)

typedef unsigned int uint32;
typedef __attribute__((ext_vector_type(8))) short bf16x8;
typedef __attribute__((ext_vector_type(4))) float f32x4;

// bf16 helpers: RNE pack, shift decode
static __device__ inline uint32 f2bf(float f) {
    uint32 u = __float_as_uint(f);
    return (u + 0x7FFFu + ((u >> 16) & 1u)) >> 16;
}
static __device__ inline float bf_lo(uint32 u) { return __uint_as_float(u << 16); }
static __device__ inline float bf_hi(uint32 u) { return __uint_as_float(u & 0xFFFF0000u); }

// ---------------- CSR build: 2-level counting sort ----------------
// R3: per-edge atomic scatter had 12x write amplification from cross-XCD
// line bouncing. Block-aggregated bucket sort keeps lines block-owned.
// R7: chunk-split gather quadruplicated per-edge overhead -> reverted.

__global__ __launch_bounds__(256) void k_bhist(const int* __restrict__ ei,
                                               int* __restrict__ bcnt) {
    __shared__ int h[NBUK];
    int t = threadIdx.x;
    for (int i = t; i < NBUK; i += 256) h[i] = 0;
    __syncthreads();
    const int4* dst4 = (const int4*)(ei + EE);
    int base4 = blockIdx.x * 4096;
    for (int j = 0; j < 16; ++j) {
        int i4 = base4 + j * 256 + t;
        if (i4 < EE / 4) {
            int4 d = dst4[i4];
            atomicAdd(&h[d.x >> 8], 1);
            atomicAdd(&h[d.y >> 8], 1);
            atomicAdd(&h[d.z >> 8], 1);
            atomicAdd(&h[d.w >> 8], 1);
        }
    }
    __syncthreads();
    for (int i = t; i < NBUK; i += 256)
        if (h[i]) atomicAdd(&bcnt[i], h[i]);
}

__global__ void k_bscan(const int* __restrict__ bcnt, int* __restrict__ bbase,
                        int* __restrict__ gcur, int* __restrict__ offs) {
    __shared__ int wsum[8];
    int t = threadIdx.x;  // 512
    int lane = t & 63, w = t >> 6;
    int c = (t < NBUK) ? bcnt[t] : 0;
    int v = c;
    for (int d = 1; d < 64; d <<= 1) { int n = __shfl_up(v, d); if (lane >= d) v += n; }
    if (lane == 63) wsum[w] = v;
    __syncthreads();
    int pre = 0;
    for (int q = 0; q < w; ++q) pre += wsum[q];
    int excl = pre + v - c;
    if (t <= NBUK) {
        bbase[t] = excl;
        if (t < NBUK) gcur[t] = excl;
    }
    if (t == 0) offs[NN] = EE;
}

// scatter packed (src<<8)|(dst&255) into CSR-ordered bucket regions
__global__ __launch_bounds__(256) void k_p1(const int* __restrict__ ei,
                                            int* __restrict__ gcur,
                                            uint32* __restrict__ pairs) {
    __shared__ int h[NBUK];
    int t = threadIdx.x;
    for (int i = t; i < NBUK; i += 256) h[i] = 0;
    __syncthreads();
    const int4* src4 = (const int4*)ei;
    const int4* dst4 = (const int4*)(ei + EE);
    int base4 = blockIdx.x * 4096;
    for (int j = 0; j < 16; ++j) {
        int i4 = base4 + j * 256 + t;
        if (i4 < EE / 4) {
            int4 d = dst4[i4];
            atomicAdd(&h[d.x >> 8], 1);
            atomicAdd(&h[d.y >> 8], 1);
            atomicAdd(&h[d.z >> 8], 1);
            atomicAdd(&h[d.w >> 8], 1);
        }
    }
    __syncthreads();
    for (int i = t; i < NBUK; i += 256) {
        int c = h[i];
        h[i] = c ? atomicAdd(&gcur[i], c) : 0;
    }
    __syncthreads();
    for (int j = 0; j < 16; ++j) {
        int i4 = base4 + j * 256 + t;
        if (i4 < EE / 4) {
            int4 d = dst4[i4];
            int4 s = src4[i4];
            int p0 = atomicAdd(&h[d.x >> 8], 1);
            pairs[p0] = ((uint32)s.x << 8) | (uint32)(d.x & 255);
            int p1 = atomicAdd(&h[d.y >> 8], 1);
            pairs[p1] = ((uint32)s.y << 8) | (uint32)(d.y & 255);
            int p2 = atomicAdd(&h[d.z >> 8], 1);
            pairs[p2] = ((uint32)s.z << 8) | (uint32)(d.z & 255);
            int p3 = atomicAdd(&h[d.w >> 8], 1);
            pairs[p3] = ((uint32)s.w << 8) | (uint32)(d.w & 255);
        }
    }
}

// per-bucket (256 nodes) CSR finalize in LDS: count, scan, scatter col
__global__ __launch_bounds__(256) void k_p2(const uint32* __restrict__ pairs,
                                            const int* __restrict__ bbase,
                                            int* __restrict__ offs, float* __restrict__ dinv,
                                            int* __restrict__ col) {
    int b = blockIdx.x, t = threadIdx.x;
    int nbase = b << 8;
    int ebase = bbase[b], eend = bbase[b + 1];
    int m = eend - ebase;
    __shared__ int cnt[256];
    __shared__ int wsum[4];
    cnt[t] = 0;
    __syncthreads();
    for (int i = t; i < m; i += 256)
        atomicAdd(&cnt[pairs[ebase + i] & 255u], 1);
    __syncthreads();
    int c = cnt[t];
    int lane = t & 63, w = t >> 6;
    int v = c;
    for (int d = 1; d < 64; d <<= 1) { int n = __shfl_up(v, d); if (lane >= d) v += n; }
    if (lane == 63) wsum[w] = v;
    __syncthreads();
    int pre = 0;
    for (int q = 0; q < w; ++q) pre += wsum[q];
    int excl = pre + v - c;
    int node = nbase + t;
    if (node < NN) {
        offs[node] = ebase + excl;
        dinv[node] = rsqrtf(1.f + (float)c);
    }
    __syncthreads();
    cnt[t] = excl;
    __syncthreads();
    for (int i = t; i < m; i += 256) {
        uint32 u = pairs[ebase + i];
        int loc = atomicAdd(&cnt[u & 255u], 1);
        col[ebase + loc] = (int)(u >> 8);
    }
}

// ------- fused setup: BN fold + W1/W2 transpose-bf16 + bcnt zero ----------
__global__ void k_setup(const float* b1, const float* g1, const float* be1,
                        const float* rm1, const float* rv1,
                        const float* b2, const float* g2, const float* be2,
                        const float* rm2, const float* rv2, float* sc,
                        const float* W1, uint32* Wt1b,
                        const float* W2, uint32* Wt2b, int* bcnt) {
    int i = blockIdx.x * 256 + threadIdx.x;
    if (i < 4096) {                       // Wt1b: K=128
        int n = i >> 6, kp = (i & 63) * 2;
        Wt1b[i] = f2bf(W1[(size_t)kp * 64 + n]) | (f2bf(W1[(size_t)(kp + 1) * 64 + n]) << 16);
    } else if (i < 6144) {                // Wt2b: K=64
        int j = i - 4096;
        int n = j >> 5, kp = (j & 31) * 2;
        Wt2b[j] = f2bf(W2[(size_t)kp * 64 + n]) | (f2bf(W2[(size_t)(kp + 1) * 64 + n]) << 16);
    } else if (i < 6208) {                // BN fold
        int l = i - 6144;
        float s1 = g1[l] * rsqrtf(rv1[l] + EPS);
        sc[l]       = s1;
        sc[64 + l]  = (b1[l] - rm1[l]) * s1 + be1[l];
        float s2 = g2[l] * rsqrtf(rv2[l] + EPS);
        sc[128 + l] = s2;
        sc[192 + l] = (b2[l] - rm2[l]) * s2 + be2[l];
    } else if (i < 6208 + NBUK) {
        bcnt[i - 6208] = 0;
    }
}

// ---------------- MFMA GEMM: [nrows,K]f32 @ [K,64]bf16 -> bf16 packed -----
// 64x64 tile/block, 4 waves x 4 n-tiles x K/32 k-steps, 16x16x32 bf16 MFMA.
// Rows padded +8 bf16: 256B-stride frag loads 16-way -> 2-way (free, m136).
template <int K>
__global__ __launch_bounds__(256) void k_gemm_mfma(const float* __restrict__ X,
                                                   const uint32* __restrict__ Wtb,
                                                   uint32* __restrict__ outb, int nrows) {
    constexpr int KP = K + 8;
    __shared__ alignas(16) unsigned short Al[64 * KP];
    __shared__ alignas(16) unsigned short Bl[64 * KP];
    int tid = threadIdx.x;
    for (int i = tid; i < 64 * (K / 2); i += 256) {
        int n = i / (K / 2), kp = i % (K / 2);
        *(uint32*)&Bl[n * KP + kp * 2] = Wtb[i];
    }
    int r0 = blockIdx.x * 64;
    const float* Xb = X + (size_t)r0 * K;
    int limit = (nrows - r0) * K;
    for (int f = tid * 4; f < 64 * K; f += 1024) {
        float4 v = {0.f, 0.f, 0.f, 0.f};
        if (f + 3 < limit) v = *(const float4*)&Xb[f];
        int row = f / K, kpos = f % K;
        ushort4 pk;
        pk.x = (unsigned short)f2bf(v.x);
        pk.y = (unsigned short)f2bf(v.y);
        pk.z = (unsigned short)f2bf(v.z);
        pk.w = (unsigned short)f2bf(v.w);
        *(ushort4*)&Al[row * KP + kpos] = pk;
    }
    __syncthreads();
    int lane = tid & 63, wv = tid >> 6;
    int m = lane & 15, quad = lane >> 4;
    f32x4 acc0 = {0.f, 0.f, 0.f, 0.f}, acc1 = acc0, acc2 = acc0, acc3 = acc0;
    int arow = wv * 16 + m;
#pragma unroll
    for (int k0 = 0; k0 < K; k0 += 32) {
        int koff = k0 + quad * 8;
        bf16x8 a = *(const bf16x8*)&Al[arow * KP + koff];
        bf16x8 b0 = *(const bf16x8*)&Bl[(0 * 16 + m) * KP + koff];
        bf16x8 b1 = *(const bf16x8*)&Bl[(1 * 16 + m) * KP + koff];
        bf16x8 b2 = *(const bf16x8*)&Bl[(2 * 16 + m) * KP + koff];
        bf16x8 b3 = *(const bf16x8*)&Bl[(3 * 16 + m) * KP + koff];
        acc0 = __builtin_amdgcn_mfma_f32_16x16x32_bf16(a, b0, acc0, 0, 0, 0);
        acc1 = __builtin_amdgcn_mfma_f32_16x16x32_bf16(a, b1, acc1, 0, 0, 0);
        acc2 = __builtin_amdgcn_mfma_f32_16x16x32_bf16(a, b2, acc2, 0, 0, 0);
        acc3 = __builtin_amdgcn_mfma_f32_16x16x32_bf16(a, b3, acc3, 0, 0, 0);
    }
    // C/D layout: col = nt*16 + m, row = quad*4 + reg.
    const float* accs[4] = {(const float*)&acc0, (const float*)&acc1,
                            (const float*)&acc2, (const float*)&acc3};
#pragma unroll
    for (int nt = 0; nt < 4; ++nt) {
#pragma unroll
        for (int reg = 0; reg < 4; ++reg) {
            float val = accs[nt][reg];
            float nxt = __shfl_down(val, 1);
            int row = r0 + wv * 16 + quad * 4 + reg;
            if (((m & 1) == 0) && row < nrows)
                outb[(size_t)row * 32 + nt * 8 + (m >> 1)] =
                    f2bf(val) | (f2bf(nxt) << 16);
        }
    }
}

// ---------- fused GCN aggregate + selfloop + BN + ReLU (+resid), bf16 ------
// One wave per node; 32 lanes cover a 128B bf16 row, 2 wave halves = 2 edges
// per load. R8: 8 edges / 4 independent loads per step for MLP; no tail loop
// (slots >= m carry w=0, shfl idx <= 63 always).
__global__ void k_gcn_gather(const uint32* __restrict__ hwb, const int* __restrict__ col,
                             const int* __restrict__ offs,
                             const float* __restrict__ dinv, const float* __restrict__ scale,
                             const float* __restrict__ shift, const float* __restrict__ resid,
                             float* __restrict__ out) {
    int node = blockIdx.x * 4 + (threadIdx.x >> 6);
    if (node >= NN) return;
    int lane = threadIdx.x & 63;
    int half = lane >> 5;
    int fl = lane & 31;                 // feature pair: {2fl, 2fl+1}
    int e0 = offs[node], e1 = offs[node + 1];
    float di = dinv[node];
    float ax0 = 0.f, ay0 = 0.f, ax1 = 0.f, ay1 = 0.f;
    for (int base = e0; base < e1; base += 64) {
        int m = e1 - base; if (m > 64) m = 64;
        int srcv = 0; float wv = 0.f;
        if (lane < m) { srcv = col[base + lane]; wv = dinv[srcv]; }
        for (int j = 0; j < m; j += 8) {
            int   s0 = __shfl(srcv, j + half);
            int   s1 = __shfl(srcv, j + 2 + half);
            int   s2 = __shfl(srcv, j + 4 + half);
            int   s3 = __shfl(srcv, j + 6 + half);
            float w0 = __shfl(wv, j + half);
            float w1 = __shfl(wv, j + 2 + half);
            float w2 = __shfl(wv, j + 4 + half);
            float w3 = __shfl(wv, j + 6 + half);
            uint32 u0 = hwb[(size_t)s0 * 32 + fl];
            uint32 u1 = hwb[(size_t)s1 * 32 + fl];
            uint32 u2 = hwb[(size_t)s2 * 32 + fl];
            uint32 u3 = hwb[(size_t)s3 * 32 + fl];
            ax0 = fmaf(bf_lo(u0), w0, ax0); ay0 = fmaf(bf_hi(u0), w0, ay0);
            ax1 = fmaf(bf_lo(u1), w1, ax1); ay1 = fmaf(bf_hi(u1), w1, ay1);
            ax0 = fmaf(bf_lo(u2), w2, ax0); ay0 = fmaf(bf_hi(u2), w2, ay0);
            ax1 = fmaf(bf_lo(u3), w3, ax1); ay1 = fmaf(bf_hi(u3), w3, ay1);
        }
    }
    float ax = ax0 + ax1, ay = ay0 + ay1;
    ax += __shfl(ax, fl + 32);
    ay += __shfl(ay, fl + 32);
    if (half == 0) {
        uint32 uself = hwb[(size_t)node * 32 + fl];
        float dii = di * di;
        float vx = fmaf(ax * di + bf_lo(uself) * dii, scale[2 * fl],     shift[2 * fl]);
        float vy = fmaf(ay * di + bf_hi(uself) * dii, scale[2 * fl + 1], shift[2 * fl + 1]);
        vx = fmaxf(vx, 0.f);
        vy = fmaxf(vy, 0.f);
        if (resid) {
            float2 rv = *(const float2*)&resid[(size_t)node * 64 + 2 * fl];
            vx += rv.x; vy += rv.y;
        }
        float2 o; o.x = vx; o.y = vy;
        *(float2*)&out[(size_t)node * 64 + 2 * fl] = o;
    }
}

// ---------------- pooling over sorted batch ----------------
__global__ void k_pool(const float* __restrict__ h, const int* __restrict__ batch,
                       float* __restrict__ msum, float* __restrict__ mmax,
                       float* __restrict__ gcnt) {
    int lane = threadIdx.x;  // 64
    int i0 = blockIdx.x * 128;
    int i1 = i0 + 128; if (i1 > NN) i1 = NN;
    int cur = batch[i0];
    float sum = 0.f, mx = 0.f; int c = 0;
    for (int i = i0; i < i1; ++i) {
        int g = batch[i];
        if (g != cur) {
            atomicAdd(&msum[cur * 64 + lane], sum);
            atomicMax((unsigned int*)&mmax[cur * 64 + lane], __float_as_uint(mx));
            if (lane == 0) atomicAdd(&gcnt[cur], (float)c);
            sum = 0.f; mx = 0.f; c = 0; cur = g;
        }
        float v = h[(long)i * 64 + lane];
        sum += v; mx = fmaxf(mx, v); ++c;
    }
    atomicAdd(&msum[cur * 64 + lane], sum);
    atomicMax((unsigned int*)&mmax[cur * 64 + lane], __float_as_uint(mx));
    if (lane == 0) atomicAdd(&gcnt[cur], (float)c);
}

// ---------------- MLP head, one block per graph ----------------
__global__ void k_head(const float* __restrict__ msum, const float* __restrict__ mmax,
                       const float* __restrict__ gcnt,
                       const float* __restrict__ Wh1, const float* __restrict__ bh1,
                       const float* __restrict__ Wh2, const float* __restrict__ bh2,
                       const float* __restrict__ Wh3, const float* __restrict__ bh3,
                       float* __restrict__ out) {
    int g = blockIdx.x, t = threadIdx.x;  // 64 threads
    __shared__ float hg[128];
    __shared__ float z1[64];
    __shared__ float z2[32];
    float c = fmaxf(gcnt[g], 1.f);
    hg[t]      = msum[g * 64 + t] / c;
    hg[64 + t] = mmax[g * 64 + t];
    __syncthreads();
    float acc = bh1[t];
#pragma unroll 8
    for (int k = 0; k < 128; ++k) acc = fmaf(hg[k], Wh1[k * 64 + t], acc);
    z1[t] = fmaxf(acc, 0.f);
    __syncthreads();
    if (t < 32) {
        float a2 = bh2[t];
#pragma unroll 8
        for (int k = 0; k < 64; ++k) a2 = fmaf(z1[k], Wh2[k * 32 + t], a2);
        z2[t] = fmaxf(a2, 0.f);
    }
    __syncthreads();
    if (t == 0) {
        float a3 = bh3[0];
        for (int k = 0; k < 32; ++k) a3 = fmaf(z2[k], Wh3[k], a3);
        out[g] = 1.f / (1.f + expf(-a3));
    }
}

// ---------------- launcher ----------------

static inline size_t alignup(size_t x) { return (x + 255) & ~(size_t)255; }

extern "C" void kernel_launch(void* const* d_in, const int* in_sizes, int n_in,
                              void* d_out, int out_size, void* d_ws, size_t ws_size,
                              hipStream_t stream) {
    const float* x   = (const float*)d_in[0];
    const int*   ei  = (const int*)d_in[1];
    const int*   bat = (const int*)d_in[2];
    const float* W1  = (const float*)d_in[3];
    const float* b1  = (const float*)d_in[4];
    const float* g1  = (const float*)d_in[5];
    const float* be1 = (const float*)d_in[6];
    const float* rm1 = (const float*)d_in[7];
    const float* rv1 = (const float*)d_in[8];
    const float* W2  = (const float*)d_in[9];
    const float* b2  = (const float*)d_in[10];
    const float* g2  = (const float*)d_in[11];
    const float* be2 = (const float*)d_in[12];
    const float* rm2 = (const float*)d_in[13];
    const float* rv2 = (const float*)d_in[14];
    const float* Wh1 = (const float*)d_in[15];
    const float* bh1 = (const float*)d_in[16];
    const float* Wh2 = (const float*)d_in[17];
    const float* bh2 = (const float*)d_in[18];
    const float* Wh3 = (const float*)d_in[19];
    const float* bh3 = (const float*)d_in[20];
    float* out = (float*)d_out;

    char* ws = (char*)d_ws;
    size_t o = 0;
    int*   bcnt   = (int*)(ws + o);  o = alignup(o + NBUK * 4);
    int*   bbase  = (int*)(ws + o);  o = alignup(o + (NBUK + 1) * 4);
    int*   gcur   = (int*)(ws + o);  o = alignup(o + NBUK * 4);
    int*   offs   = (int*)(ws + o);  o = alignup(o + (NN + 1) * 4);
    uint32* pairs = (uint32*)(ws + o); o = alignup(o + (size_t)EE * 4);
    int*   col    = (int*)(ws + o);  o = alignup(o + (size_t)EE * 4);
    float* dinv   = (float*)(ws + o); o = alignup(o + (size_t)NN * 4);
    float* scb    = (float*)(ws + o); o = alignup(o + 4 * 64 * 4);
    uint32* Wt1b  = (uint32*)(ws + o); o = alignup(o + 64 * (INF_ / 2) * 4);
    uint32* Wt2b  = (uint32*)(ws + o); o = alignup(o + 64 * (HID / 2) * 4);
    float* msum   = (float*)(ws + o);
    size_t pool_off = o;              o += (size_t)GG * 64 * 4;
    float* mmax   = (float*)(ws + o); o += (size_t)GG * 64 * 4;
    float* gcnt   = (float*)(ws + o); o += (size_t)GG * 4;
    size_t pool_bytes = o - pool_off; o = alignup(o);
    uint32* hwb   = (uint32*)(ws + o); o = alignup(o + (size_t)NN * 32 * 4);
    float* h      = (float*)(ws + o); o = alignup(o + (size_t)NN * 64 * 4);
    (void)ws_size; (void)n_in; (void)in_sizes; (void)out_size;

    hipMemsetAsync(ws + pool_off, 0, pool_bytes, stream);

    k_setup<<<26, 256, 0, stream>>>(b1, g1, be1, rm1, rv1, b2, g2, be2, rm2, rv2,
                                    scb, W1, Wt1b, W2, Wt2b, bcnt);
    k_bhist<<<P1_TILES, 256, 0, stream>>>(ei, bcnt);
    k_bscan<<<1, 512, 0, stream>>>(bcnt, bbase, gcur, offs);
    k_p1<<<P1_TILES, 256, 0, stream>>>(ei, gcur, pairs);
    k_p2<<<NBUK, 256, 0, stream>>>(pairs, bbase, offs, dinv, col);

    // layer 1
    k_gemm_mfma<INF_><<<(NN + 63) / 64, 256, 0, stream>>>(x, Wt1b, hwb, NN);
    k_gcn_gather<<<(NN + 3) / 4, 256, 0, stream>>>(hwb, col, offs, dinv,
                                                   scb, scb + 64, nullptr, h);
    // layer 2 (residual, in-place into h)
    k_gemm_mfma<HID><<<(NN + 63) / 64, 256, 0, stream>>>(h, Wt2b, hwb, NN);
    k_gcn_gather<<<(NN + 3) / 4, 256, 0, stream>>>(hwb, col, offs, dinv,
                                                   scb + 128, scb + 192, h, h);
    // pooling + head
    k_pool<<<(NN + 127) / 128, 64, 0, stream>>>(h, bat, msum, mmax, gcnt);
    k_head<<<GG, 64, 0, stream>>>(msum, mmax, gcnt, Wh1, bh1, Wh2, bh2, Wh3, bh3, out);
}

// Round 9
// 303.311 us; speedup vs baseline: 1.6835x; 1.1046x over previous
//
#include <hip/hip_runtime.h>
#include <math.h>

#define NN 100000
#define EE 1600000
#define GG 512
#define INF_ 128
#define HID 64
#define EPS 1e-5f

#define NBUK 391          // ceil(NN/256), bucket = dst >> 8
#define P1_TILES 98       // ceil((EE/4)/4096)
#define SETUP_B 25        // ceil(6208/256)
#define POOL_WORDS (GG * 64 * 2 + GG)
#define ZERO_B ((POOL_WORDS + 255) / 256)

typedef unsigned int uint32;
typedef __attribute__((ext_vector_type(8))) short bf16x8;
typedef __attribute__((ext_vector_type(4))) float f32x4;

// bf16 helpers: RNE pack, shift decode
static __device__ inline uint32 f2bf(float f) {
    uint32 u = __float_as_uint(f);
    return (u + 0x7FFFu + ((u >> 16) & 1u)) >> 16;
}
static __device__ inline float bf_lo(uint32 u) { return __uint_as_float(u << 16); }
static __device__ inline float bf_hi(uint32 u) { return __uint_as_float(u & 0xFFFF0000u); }

// ---------------- CSR build: 2-level counting sort, single-histogram ------
// R3: per-edge atomic scatter -> 12x cross-XCD write amplification; bucketed.
// R7: chunk-split gather quadruplicated per-edge overhead -> reverted.
// R9: hist computed ONCE into per-block hblk; scan2 derives per-(block,bucket)
// run bases deterministically; p1b only scatters. Setup + pool-zero fused.

// blocks [0,98): per-block dst histogram -> hblk. [98,123): setup. rest: zero pool.
__global__ __launch_bounds__(256) void k_hist1(const int* __restrict__ ei,
        int* __restrict__ hblk,
        const float* b1, const float* g1, const float* be1,
        const float* rm1, const float* rv1,
        const float* b2, const float* g2, const float* be2,
        const float* rm2, const float* rv2, float* sc,
        const float* W1, uint32* Wt1b, const float* W2, uint32* Wt2b,
        float* poolz) {
    int b = blockIdx.x, t = threadIdx.x;
    if (b < P1_TILES) {
        __shared__ int h[NBUK];
        for (int i = t; i < NBUK; i += 256) h[i] = 0;
        __syncthreads();
        const int4* dst4 = (const int4*)(ei + EE);
        int base4 = b * 4096;
        for (int j = 0; j < 16; ++j) {
            int i4 = base4 + j * 256 + t;
            if (i4 < EE / 4) {
                int4 d = dst4[i4];
                atomicAdd(&h[d.x >> 8], 1);
                atomicAdd(&h[d.y >> 8], 1);
                atomicAdd(&h[d.z >> 8], 1);
                atomicAdd(&h[d.w >> 8], 1);
            }
        }
        __syncthreads();
        for (int i = t; i < NBUK; i += 256) hblk[b * NBUK + i] = h[i];
    } else if (b < P1_TILES + SETUP_B) {
        int i = (b - P1_TILES) * 256 + t;
        if (i < 4096) {                       // Wt1b: K=128
            int n = i >> 6, kp = (i & 63) * 2;
            Wt1b[i] = f2bf(W1[(size_t)kp * 64 + n]) |
                      (f2bf(W1[(size_t)(kp + 1) * 64 + n]) << 16);
        } else if (i < 6144) {                // Wt2b: K=64
            int j = i - 4096;
            int n = j >> 5, kp = (j & 31) * 2;
            Wt2b[j] = f2bf(W2[(size_t)kp * 64 + n]) |
                      (f2bf(W2[(size_t)(kp + 1) * 64 + n]) << 16);
        } else if (i < 6208) {                // BN fold
            int l = i - 6144;
            float s1 = g1[l] * rsqrtf(rv1[l] + EPS);
            sc[l]       = s1;
            sc[64 + l]  = (b1[l] - rm1[l]) * s1 + be1[l];
            float s2 = g2[l] * rsqrtf(rv2[l] + EPS);
            sc[128 + l] = s2;
            sc[192 + l] = (b2[l] - rm2[l]) * s2 + be2[l];
        }
    } else {
        int i = (b - P1_TILES - SETUP_B) * 256 + t;
        if (i < POOL_WORDS) poolz[i] = 0.f;
    }
}

// one block, 512 threads: bucket totals, bucket scan -> bbase, per-block run
// bases -> rbase[98][NBUK]. All deterministic, no atomics.
__global__ void k_scan2(const int* __restrict__ hblk, int* __restrict__ bbase,
                        int* __restrict__ rbase, int* __restrict__ offs) {
    __shared__ int wsum[8];
    int t = threadIdx.x;  // 512
    int lane = t & 63, w = t >> 6;
    int c = 0;
    if (t < NBUK)
        for (int b = 0; b < P1_TILES; ++b) c += hblk[b * NBUK + t];
    int v = c;
    for (int d = 1; d < 64; d <<= 1) { int n = __shfl_up(v, d); if (lane >= d) v += n; }
    if (lane == 63) wsum[w] = v;
    __syncthreads();
    int pre = 0;
    for (int q = 0; q < w; ++q) pre += wsum[q];
    int excl = pre + v - c;
    if (t <= NBUK) bbase[t] = excl;
    if (t == 0) offs[NN] = EE;
    if (t < NBUK) {
        int run = excl;
        for (int b = 0; b < P1_TILES; ++b) {
            rbase[b * NBUK + t] = run;
            run += hblk[b * NBUK + t];
        }
    }
}

// scatter packed (src<<8)|(dst&255) into CSR-ordered bucket regions
__global__ __launch_bounds__(256) void k_p1b(const int* __restrict__ ei,
                                             const int* __restrict__ rbase,
                                             uint32* __restrict__ pairs) {
    __shared__ int h[NBUK];
    int b = blockIdx.x, t = threadIdx.x;
    for (int i = t; i < NBUK; i += 256) h[i] = rbase[b * NBUK + i];
    __syncthreads();
    const int4* src4 = (const int4*)ei;
    const int4* dst4 = (const int4*)(ei + EE);
    int base4 = b * 4096;
    for (int j = 0; j < 16; ++j) {
        int i4 = base4 + j * 256 + t;
        if (i4 < EE / 4) {
            int4 d = dst4[i4];
            int4 s = src4[i4];
            int p0 = atomicAdd(&h[d.x >> 8], 1);
            pairs[p0] = ((uint32)s.x << 8) | (uint32)(d.x & 255);
            int p1 = atomicAdd(&h[d.y >> 8], 1);
            pairs[p1] = ((uint32)s.y << 8) | (uint32)(d.y & 255);
            int p2 = atomicAdd(&h[d.z >> 8], 1);
            pairs[p2] = ((uint32)s.z << 8) | (uint32)(d.z & 255);
            int p3 = atomicAdd(&h[d.w >> 8], 1);
            pairs[p3] = ((uint32)s.w << 8) | (uint32)(d.w & 255);
        }
    }
}

// per-bucket (256 nodes) CSR finalize in LDS: count, scan, scatter col
__global__ __launch_bounds__(256) void k_p2(const uint32* __restrict__ pairs,
                                            const int* __restrict__ bbase,
                                            int* __restrict__ offs, float* __restrict__ dinv,
                                            int* __restrict__ col) {
    int b = blockIdx.x, t = threadIdx.x;
    int nbase = b << 8;
    int ebase = bbase[b], eend = bbase[b + 1];
    int m = eend - ebase;
    __shared__ int cnt[256];
    __shared__ int wsum[4];
    cnt[t] = 0;
    __syncthreads();
    for (int i = t; i < m; i += 256)
        atomicAdd(&cnt[pairs[ebase + i] & 255u], 1);
    __syncthreads();
    int c = cnt[t];
    int lane = t & 63, w = t >> 6;
    int v = c;
    for (int d = 1; d < 64; d <<= 1) { int n = __shfl_up(v, d); if (lane >= d) v += n; }
    if (lane == 63) wsum[w] = v;
    __syncthreads();
    int pre = 0;
    for (int q = 0; q < w; ++q) pre += wsum[q];
    int excl = pre + v - c;
    int node = nbase + t;
    if (node < NN) {
        offs[node] = ebase + excl;
        dinv[node] = rsqrtf(1.f + (float)c);
    }
    __syncthreads();
    cnt[t] = excl;
    __syncthreads();
    for (int i = t; i < m; i += 256) {
        uint32 u = pairs[ebase + i];
        int loc = atomicAdd(&cnt[u & 255u], 1);
        col[ebase + loc] = (int)(u >> 8);
    }
}

// ---------------- MFMA GEMM: [nrows,K]f32 @ [K,64]bf16 -> bf16 packed -----
// 64x64 tile/block, 4 waves x 4 n-tiles x K/32 k-steps, 16x16x32 bf16 MFMA.
// Rows padded +8 bf16: 256B-stride frag loads 16-way -> 2-way (free, m136).
template <int K>
__global__ __launch_bounds__(256) void k_gemm_mfma(const float* __restrict__ X,
                                                   const uint32* __restrict__ Wtb,
                                                   uint32* __restrict__ outb, int nrows) {
    constexpr int KP = K + 8;
    __shared__ alignas(16) unsigned short Al[64 * KP];
    __shared__ alignas(16) unsigned short Bl[64 * KP];
    int tid = threadIdx.x;
    for (int i = tid; i < 64 * (K / 2); i += 256) {
        int n = i / (K / 2), kp = i % (K / 2);
        *(uint32*)&Bl[n * KP + kp * 2] = Wtb[i];
    }
    int r0 = blockIdx.x * 64;
    const float* Xb = X + (size_t)r0 * K;
    int limit = (nrows - r0) * K;
    for (int f = tid * 4; f < 64 * K; f += 1024) {
        float4 v = {0.f, 0.f, 0.f, 0.f};
        if (f + 3 < limit) v = *(const float4*)&Xb[f];
        int row = f / K, kpos = f % K;
        ushort4 pk;
        pk.x = (unsigned short)f2bf(v.x);
        pk.y = (unsigned short)f2bf(v.y);
        pk.z = (unsigned short)f2bf(v.z);
        pk.w = (unsigned short)f2bf(v.w);
        *(ushort4*)&Al[row * KP + kpos] = pk;
    }
    __syncthreads();
    int lane = tid & 63, wv = tid >> 6;
    int m = lane & 15, quad = lane >> 4;
    f32x4 acc0 = {0.f, 0.f, 0.f, 0.f}, acc1 = acc0, acc2 = acc0, acc3 = acc0;
    int arow = wv * 16 + m;
#pragma unroll
    for (int k0 = 0; k0 < K; k0 += 32) {
        int koff = k0 + quad * 8;
        bf16x8 a = *(const bf16x8*)&Al[arow * KP + koff];
        bf16x8 b0 = *(const bf16x8*)&Bl[(0 * 16 + m) * KP + koff];
        bf16x8 b1 = *(const bf16x8*)&Bl[(1 * 16 + m) * KP + koff];
        bf16x8 b2 = *(const bf16x8*)&Bl[(2 * 16 + m) * KP + koff];
        bf16x8 b3 = *(const bf16x8*)&Bl[(3 * 16 + m) * KP + koff];
        acc0 = __builtin_amdgcn_mfma_f32_16x16x32_bf16(a, b0, acc0, 0, 0, 0);
        acc1 = __builtin_amdgcn_mfma_f32_16x16x32_bf16(a, b1, acc1, 0, 0, 0);
        acc2 = __builtin_amdgcn_mfma_f32_16x16x32_bf16(a, b2, acc2, 0, 0, 0);
        acc3 = __builtin_amdgcn_mfma_f32_16x16x32_bf16(a, b3, acc3, 0, 0, 0);
    }
    // C/D layout: col = nt*16 + m, row = quad*4 + reg.
    const float* accs[4] = {(const float*)&acc0, (const float*)&acc1,
                            (const float*)&acc2, (const float*)&acc3};
#pragma unroll
    for (int nt = 0; nt < 4; ++nt) {
#pragma unroll
        for (int reg = 0; reg < 4; ++reg) {
            float val = accs[nt][reg];
            float nxt = __shfl_down(val, 1);
            int row = r0 + wv * 16 + quad * 4 + reg;
            if (((m & 1) == 0) && row < nrows)
                outb[(size_t)row * 32 + nt * 8 + (m >> 1)] =
                    f2bf(val) | (f2bf(nxt) << 16);
        }
    }
}

// ---------- fused GCN aggregate + selfloop + BN + ReLU (+resid), bf16 ------
// One wave per node; 32 lanes cover a 128B bf16 row, 2 wave halves = 2 edges
// per load. R9: 16 edges / 8 loads in flight per step; slots >= m load hot
// row 0 with w=0 (harmless). shfl idx <= 48+15 = 63 always.
__global__ void k_gcn_gather(const uint32* __restrict__ hwb, const int* __restrict__ col,
                             const int* __restrict__ offs,
                             const float* __restrict__ dinv, const float* __restrict__ scale,
                             const float* __restrict__ shift, const float* __restrict__ resid,
                             float* __restrict__ out) {
    int node = blockIdx.x * 4 + (threadIdx.x >> 6);
    if (node >= NN) return;
    int lane = threadIdx.x & 63;
    int half = lane >> 5;
    int fl = lane & 31;                 // feature pair: {2fl, 2fl+1}
    int e0 = offs[node], e1 = offs[node + 1];
    float di = dinv[node];
    float ax0 = 0.f, ay0 = 0.f, ax1 = 0.f, ay1 = 0.f;
    for (int base = e0; base < e1; base += 64) {
        int m = e1 - base; if (m > 64) m = 64;
        int srcv = 0; float wv = 0.f;
        if (lane < m) { srcv = col[base + lane]; wv = dinv[srcv]; }
        for (int j = 0; j < m; j += 16) {
            int   s0 = __shfl(srcv, j + half);
            int   s1 = __shfl(srcv, j + 2 + half);
            int   s2 = __shfl(srcv, j + 4 + half);
            int   s3 = __shfl(srcv, j + 6 + half);
            int   s4 = __shfl(srcv, j + 8 + half);
            int   s5 = __shfl(srcv, j + 10 + half);
            int   s6 = __shfl(srcv, j + 12 + half);
            int   s7 = __shfl(srcv, j + 14 + half);
            float w0 = __shfl(wv, j + half);
            float w1 = __shfl(wv, j + 2 + half);
            float w2 = __shfl(wv, j + 4 + half);
            float w3 = __shfl(wv, j + 6 + half);
            float w4 = __shfl(wv, j + 8 + half);
            float w5 = __shfl(wv, j + 10 + half);
            float w6 = __shfl(wv, j + 12 + half);
            float w7 = __shfl(wv, j + 14 + half);
            uint32 u0 = hwb[(size_t)s0 * 32 + fl];
            uint32 u1 = hwb[(size_t)s1 * 32 + fl];
            uint32 u2 = hwb[(size_t)s2 * 32 + fl];
            uint32 u3 = hwb[(size_t)s3 * 32 + fl];
            uint32 u4 = hwb[(size_t)s4 * 32 + fl];
            uint32 u5 = hwb[(size_t)s5 * 32 + fl];
            uint32 u6 = hwb[(size_t)s6 * 32 + fl];
            uint32 u7 = hwb[(size_t)s7 * 32 + fl];
            ax0 = fmaf(bf_lo(u0), w0, ax0); ay0 = fmaf(bf_hi(u0), w0, ay0);
            ax1 = fmaf(bf_lo(u1), w1, ax1); ay1 = fmaf(bf_hi(u1), w1, ay1);
            ax0 = fmaf(bf_lo(u2), w2, ax0); ay0 = fmaf(bf_hi(u2), w2, ay0);
            ax1 = fmaf(bf_lo(u3), w3, ax1); ay1 = fmaf(bf_hi(u3), w3, ay1);
            ax0 = fmaf(bf_lo(u4), w4, ax0); ay0 = fmaf(bf_hi(u4), w4, ay0);
            ax1 = fmaf(bf_lo(u5), w5, ax1); ay1 = fmaf(bf_hi(u5), w5, ay1);
            ax0 = fmaf(bf_lo(u6), w6, ax0); ay0 = fmaf(bf_hi(u6), w6, ay0);
            ax1 = fmaf(bf_lo(u7), w7, ax1); ay1 = fmaf(bf_hi(u7), w7, ay1);
        }
    }
    float ax = ax0 + ax1, ay = ay0 + ay1;
    ax += __shfl(ax, fl + 32);
    ay += __shfl(ay, fl + 32);
    if (half == 0) {
        uint32 uself = hwb[(size_t)node * 32 + fl];
        float dii = di * di;
        float vx = fmaf(ax * di + bf_lo(uself) * dii, scale[2 * fl],     shift[2 * fl]);
        float vy = fmaf(ay * di + bf_hi(uself) * dii, scale[2 * fl + 1], shift[2 * fl + 1]);
        vx = fmaxf(vx, 0.f);
        vy = fmaxf(vy, 0.f);
        if (resid) {
            float2 rv = *(const float2*)&resid[(size_t)node * 64 + 2 * fl];
            vx += rv.x; vy += rv.y;
        }
        float2 o; o.x = vx; o.y = vy;
        *(float2*)&out[(size_t)node * 64 + 2 * fl] = o;
    }
}

// ---------------- pooling over sorted batch, 4 waves x 32 nodes -----------
__global__ __launch_bounds__(256) void k_pool(const float* __restrict__ h,
                       const int* __restrict__ batch,
                       float* __restrict__ msum, float* __restrict__ mmax,
                       float* __restrict__ gcnt) {
    int lane = threadIdx.x & 63;
    int wv = threadIdx.x >> 6;
    int i0 = blockIdx.x * 128 + wv * 32;
    if (i0 >= NN) return;
    int i1 = i0 + 32; if (i1 > NN) i1 = NN;
    int cur = batch[i0];
    float sum = 0.f, mx = 0.f; int c = 0;
    for (int i = i0; i < i1; ++i) {
        int g = batch[i];
        if (g != cur) {
            atomicAdd(&msum[cur * 64 + lane], sum);
            atomicMax((unsigned int*)&mmax[cur * 64 + lane], __float_as_uint(mx));
            if (lane == 0) atomicAdd(&gcnt[cur], (float)c);
            sum = 0.f; mx = 0.f; c = 0; cur = g;
        }
        float v = h[(long)i * 64 + lane];
        sum += v; mx = fmaxf(mx, v); ++c;
    }
    atomicAdd(&msum[cur * 64 + lane], sum);
    atomicMax((unsigned int*)&mmax[cur * 64 + lane], __float_as_uint(mx));
    if (lane == 0) atomicAdd(&gcnt[cur], (float)c);
}

// ---------------- MLP head, one block per graph ----------------
__global__ void k_head(const float* __restrict__ msum, const float* __restrict__ mmax,
                       const float* __restrict__ gcnt,
                       const float* __restrict__ Wh1, const float* __restrict__ bh1,
                       const float* __restrict__ Wh2, const float* __restrict__ bh2,
                       const float* __restrict__ Wh3, const float* __restrict__ bh3,
                       float* __restrict__ out) {
    int g = blockIdx.x, t = threadIdx.x;  // 64 threads
    __shared__ float hg[128];
    __shared__ float z1[64];
    __shared__ float z2[32];
    float c = fmaxf(gcnt[g], 1.f);
    hg[t]      = msum[g * 64 + t] / c;
    hg[64 + t] = mmax[g * 64 + t];
    __syncthreads();
    float acc = bh1[t];
#pragma unroll 8
    for (int k = 0; k < 128; ++k) acc = fmaf(hg[k], Wh1[k * 64 + t], acc);
    z1[t] = fmaxf(acc, 0.f);
    __syncthreads();
    if (t < 32) {
        float a2 = bh2[t];
#pragma unroll 8
        for (int k = 0; k < 64; ++k) a2 = fmaf(z1[k], Wh2[k * 32 + t], a2);
        z2[t] = fmaxf(a2, 0.f);
    }
    __syncthreads();
    if (t == 0) {
        float a3 = bh3[0];
        for (int k = 0; k < 32; ++k) a3 = fmaf(z2[k], Wh3[k], a3);
        out[g] = 1.f / (1.f + expf(-a3));
    }
}

// ---------------- launcher ----------------

static inline size_t alignup(size_t x) { return (x + 255) & ~(size_t)255; }

extern "C" void kernel_launch(void* const* d_in, const int* in_sizes, int n_in,
                              void* d_out, int out_size, void* d_ws, size_t ws_size,
                              hipStream_t stream) {
    const float* x   = (const float*)d_in[0];
    const int*   ei  = (const int*)d_in[1];
    const int*   bat = (const int*)d_in[2];
    const float* W1  = (const float*)d_in[3];
    const float* b1  = (const float*)d_in[4];
    const float* g1  = (const float*)d_in[5];
    const float* be1 = (const float*)d_in[6];
    const float* rm1 = (const float*)d_in[7];
    const float* rv1 = (const float*)d_in[8];
    const float* W2  = (const float*)d_in[9];
    const float* b2  = (const float*)d_in[10];
    const float* g2  = (const float*)d_in[11];
    const float* be2 = (const float*)d_in[12];
    const float* rm2 = (const float*)d_in[13];
    const float* rv2 = (const float*)d_in[14];
    const float* Wh1 = (const float*)d_in[15];
    const float* bh1 = (const float*)d_in[16];
    const float* Wh2 = (const float*)d_in[17];
    const float* bh2 = (const float*)d_in[18];
    const float* Wh3 = (const float*)d_in[19];
    const float* bh3 = (const float*)d_in[20];
    float* out = (float*)d_out;

    char* ws = (char*)d_ws;
    size_t o = 0;
    int*   hblk   = (int*)(ws + o);  o = alignup(o + (size_t)P1_TILES * NBUK * 4);
    int*   rbase  = (int*)(ws + o);  o = alignup(o + (size_t)P1_TILES * NBUK * 4);
    int*   bbase  = (int*)(ws + o);  o = alignup(o + (NBUK + 1) * 4);
    int*   offs   = (int*)(ws + o);  o = alignup(o + (NN + 1) * 4);
    uint32* pairs = (uint32*)(ws + o); o = alignup(o + (size_t)EE * 4);
    int*   col    = (int*)(ws + o);  o = alignup(o + (size_t)EE * 4);
    float* dinv   = (float*)(ws + o); o = alignup(o + (size_t)NN * 4);
    float* scb    = (float*)(ws + o); o = alignup(o + 4 * 64 * 4);
    uint32* Wt1b  = (uint32*)(ws + o); o = alignup(o + 64 * (INF_ / 2) * 4);
    uint32* Wt2b  = (uint32*)(ws + o); o = alignup(o + 64 * (HID / 2) * 4);
    float* msum   = (float*)(ws + o); o += (size_t)GG * 64 * 4;
    float* mmax   = (float*)(ws + o); o += (size_t)GG * 64 * 4;
    float* gcnt   = (float*)(ws + o); o += (size_t)GG * 4;
    o = alignup(o);
    uint32* hwb   = (uint32*)(ws + o); o = alignup(o + (size_t)NN * 32 * 4);
    float* h      = (float*)(ws + o); o = alignup(o + (size_t)NN * 64 * 4);
    (void)ws_size; (void)n_in; (void)in_sizes; (void)out_size;

    // CSR build + setup + pool-zero (one kernel, 3 block roles)
    k_hist1<<<P1_TILES + SETUP_B + ZERO_B, 256, 0, stream>>>(
        ei, hblk, b1, g1, be1, rm1, rv1, b2, g2, be2, rm2, rv2, scb,
        W1, Wt1b, W2, Wt2b, msum);
    k_scan2<<<1, 512, 0, stream>>>(hblk, bbase, rbase, offs);
    k_p1b<<<P1_TILES, 256, 0, stream>>>(ei, rbase, pairs);
    k_p2<<<NBUK, 256, 0, stream>>>(pairs, bbase, offs, dinv, col);

    // layer 1
    k_gemm_mfma<INF_><<<(NN + 63) / 64, 256, 0, stream>>>(x, Wt1b, hwb, NN);
    k_gcn_gather<<<(NN + 3) / 4, 256, 0, stream>>>(hwb, col, offs, dinv,
                                                   scb, scb + 64, nullptr, h);
    // layer 2 (residual, in-place into h)
    k_gemm_mfma<HID><<<(NN + 63) / 64, 256, 0, stream>>>(h, Wt2b, hwb, NN);
    k_gcn_gather<<<(NN + 3) / 4, 256, 0, stream>>>(hwb, col, offs, dinv,
                                                   scb + 128, scb + 192, h, h);
    // pooling + head
    k_pool<<<(NN + 127) / 128, 256, 0, stream>>>(h, bat, msum, mmax, gcnt);
    k_head<<<GG, 64, 0, stream>>>(msum, mmax, gcnt, Wh1, bh1, Wh2, bh2, Wh3, bh3, out);
}